// Round 6
// baseline (760.261 us; speedup 1.0000x reference)
//
#include <hip/hip_runtime.h>
#include <math.h>

#define D_MODEL 1024
#define NUM_HEADS 16
#define D_HEAD 64
#define SEQ 2048
#define BATCH 2

typedef __attribute__((ext_vector_type(8))) short short8;
typedef __attribute__((ext_vector_type(4))) float float4v;

__device__ __forceinline__ short f2bf(float f) {
    unsigned u = __float_as_uint(f);
    u += 0x7FFFu + ((u >> 16) & 1u);
    return (short)(u >> 16);
}

// ---------------------------------------------------------------------------
// Kernel 0: fp32 -> bf16 conversion for x and the four weight matrices.
// ---------------------------------------------------------------------------
__global__ __launch_bounds__(256) void cvt_bf16_kernel(
    const float* __restrict__ x,  const float* __restrict__ wq,
    const float* __restrict__ wk, const float* __restrict__ wv,
    const float* __restrict__ wo,
    short* __restrict__ xb,  short* __restrict__ wqb,
    short* __restrict__ wkb, short* __restrict__ wvb,
    short* __restrict__ wob)
{
    const int a = blockIdx.y;
    const float* src = (a == 0) ? x : (a == 1) ? wq : (a == 2) ? wk : (a == 3) ? wv : wo;
    short* dst = (a == 0) ? xb : (a == 1) ? wqb : (a == 2) ? wkb : (a == 3) ? wvb : wob;
    const int n = (a == 0) ? (BATCH * SEQ * D_MODEL) : (D_MODEL * D_MODEL);
    const int i = (blockIdx.x * 256 + threadIdx.x) * 8;
    if (i >= n) return;
    const float4 v0 = *(const float4*)(src + i);
    const float4 v1 = *(const float4*)(src + i + 4);
    short8 r;
    r[0] = f2bf(v0.x); r[1] = f2bf(v0.y); r[2] = f2bf(v0.z); r[3] = f2bf(v0.w);
    r[4] = f2bf(v1.x); r[5] = f2bf(v1.y); r[6] = f2bf(v1.z); r[7] = f2bf(v1.w);
    *(short8*)(dst + i) = r;
}

// ---------------------------------------------------------------------------
// bf16 MFMA GEMM core, register-prefetch + double-buffered LDS, one barrier
// per K-step. A-operand loads are NONTEMPORAL: the A working set of the
// co-resident block cohort (~8 MB) cannot fit a 4 MB per-XCD L2, so we
// stream it and reserve L2 for the (2 MB, phase-shared) B weight matrix.
// ---------------------------------------------------------------------------
__device__ __forceinline__ void gemm_core_db(
    const short* __restrict__ a, const short* __restrict__ b,
    short* smem, int m0, int n0, float4v acc[4][4])
{
    const int tid = threadIdx.x;
    const int lane = tid & 63;
    const int l15 = lane & 15, quad = lane >> 4;
    const int wave = tid >> 6;
    const int mw = (wave & 1) * 64, nw = (wave >> 1) * 64;
    const int srow = tid >> 2;            // 0..63
    const int scol = (tid & 3) * 8;       // 0,8,16,24

    const short* ag = a + (size_t)(m0 + srow) * D_MODEL + scol;
    const short* bg = b + (size_t)(n0 + srow) * D_MODEL + scol;

    short* bufA[2] = { smem,        smem + 8192 };
    short* bufB[2] = { smem + 4096, smem + 12288 };

    // prologue: stage k=0, prefetch k=1
    short8 ga0 = __builtin_nontemporal_load((const short8*)(ag));
    short8 ga1 = __builtin_nontemporal_load((const short8*)(ag + (size_t)64 * D_MODEL));
    short8 gb0 = *(const short8*)(bg);
    short8 gb1 = *(const short8*)(bg + (size_t)64 * D_MODEL);
    *(short8*)&bufA[0][srow * 32 + scol]        = ga0;
    *(short8*)&bufA[0][(64 + srow) * 32 + scol] = ga1;
    *(short8*)&bufB[0][srow * 32 + scol]        = gb0;
    *(short8*)&bufB[0][(64 + srow) * 32 + scol] = gb1;
    ga0 = __builtin_nontemporal_load((const short8*)(ag + 32));
    ga1 = __builtin_nontemporal_load((const short8*)(ag + 32 + (size_t)64 * D_MODEL));
    gb0 = *(const short8*)(bg + 32);
    gb1 = *(const short8*)(bg + 32 + (size_t)64 * D_MODEL);

    for (int k = 0; k < 32; k++) {
        __syncthreads();                       // buf[k&1] visible; buf[(k+1)&1] free
        if (k + 1 < 32) {                      // regs hold k+1 data
            short* bA = bufA[(k + 1) & 1];
            short* bB = bufB[(k + 1) & 1];
            *(short8*)&bA[srow * 32 + scol]        = ga0;
            *(short8*)&bA[(64 + srow) * 32 + scol] = ga1;
            *(short8*)&bB[srow * 32 + scol]        = gb0;
            *(short8*)&bB[(64 + srow) * 32 + scol] = gb1;
        }
        if (k + 2 < 32) {                      // prefetch k+2
            const int off = (k + 2) * 32;
            ga0 = __builtin_nontemporal_load((const short8*)(ag + off));
            ga1 = __builtin_nontemporal_load((const short8*)(ag + off + (size_t)64 * D_MODEL));
            gb0 = *(const short8*)(bg + off);
            gb1 = *(const short8*)(bg + off + (size_t)64 * D_MODEL);
        }
        const short* lA = bufA[k & 1];
        const short* lB = bufB[k & 1];
        short8 af[4], bf[4];
        #pragma unroll
        for (int i = 0; i < 4; i++)
            af[i] = *(const short8*)&lA[(mw + i * 16 + l15) * 32 + quad * 8];
        #pragma unroll
        for (int i = 0; i < 4; i++)
            bf[i] = *(const short8*)&lB[(nw + i * 16 + l15) * 32 + quad * 8];
        #pragma unroll
        for (int mi = 0; mi < 4; mi++)
            #pragma unroll
            for (int ni = 0; ni < 4; ni++)
                acc[mi][ni] = __builtin_amdgcn_mfma_f32_16x16x32_bf16(
                    af[mi], bf[ni], acc[mi][ni], 0, 0, 0);
    }
}

// ---------------------------------------------------------------------------
// Kernel 1: QKV projection (bf16 MFMA) + fused RoPE epilogue.
// Launch-order mapping bid = z*256 + n*32 + m: the co-resident cohort all
// works on ONE z (2 MB weight, fits every per-XCD L2) at the SAME k-phase,
// so weight lines get their reuse before eviction. No manual XCD swizzle
// (round-5 counters: bid&7 swizzle doubled FETCH and cost 90 us).
// ---------------------------------------------------------------------------
__global__ __launch_bounds__(256) void qkv_mfma_kernel(
    const short* __restrict__ xb, const short* __restrict__ wqb,
    const short* __restrict__ wkb, const short* __restrict__ wvb,
    const int* __restrict__ pos,
    short* __restrict__ Qb, short* __restrict__ Kb, short* __restrict__ Vt)
{
    __shared__ __align__(16) short smem[128 * 136];   // 34816 B (gemm uses 32 KB)

    const int bid = blockIdx.x;
    const int z = bid >> 8;                // 0..2
    const int m0 = (bid & 31) * 128;       // m fastest -> cohort shares weight
    const int n0 = ((bid >> 5) & 7) * 128;

    const short* w = (z == 0) ? wqb : (z == 1) ? wkb : wvb;

    float4v acc[4][4];
    #pragma unroll
    for (int i = 0; i < 4; i++)
        #pragma unroll
        for (int j = 0; j < 4; j++)
            acc[i][j] = (float4v){0.f, 0.f, 0.f, 0.f};

    gemm_core_db(xb, w, smem, m0, n0, acc);

    const int tid = threadIdx.x;
    const int lane = tid & 63;
    const int l15 = lane & 15, quad = lane >> 4;
    const int wave = tid >> 6;
    const int mw = (wave & 1) * 64, nw = (wave >> 1) * 64;

    const int s_base = m0 & (SEQ - 1);
    const int bb = m0 >> 11;              // tile never crosses batch (128|2048)

    __syncthreads();                      // gemm LDS reads done; reuse smem

    if (z == 2) {
        // stage transposed [n][m], stride 136
        #pragma unroll
        for (int ni = 0; ni < 4; ni++) {
            #pragma unroll
            for (int mi = 0; mi < 4; mi++) {
                #pragma unroll
                for (int r = 0; r < 4; r++)
                    smem[(nw + ni * 16 + l15) * 136 + mw + mi * 16 + quad * 4 + r] =
                        f2bf(acc[mi][ni][r]);
            }
        }
        __syncthreads();
        #pragma unroll
        for (int it = 0; it < 8; it++) {
            const int nloc = it * 16 + (tid >> 4);
            const int mloc = (tid & 15) * 8;
            const short8 val = *(const short8*)&smem[nloc * 136 + mloc];
            const int n = n0 + nloc;
            const int h = n >> 6, d = n & 63;
            *(short8*)(Vt + ((size_t)(bb * NUM_HEADS + h) * D_HEAD + d) * SEQ +
                       s_base + mloc) = val;
        }
    } else {
        short* dst = (z == 0) ? Qb : Kb;
        const float qs = (z == 0) ? 0.125f : 1.0f;
        #pragma unroll
        for (int ni = 0; ni < 4; ni++) {
            const int n = n0 + nw + ni * 16 + l15;
            const int d = n & 63;
            const int fi = d >> 1;
            const float inv_freq = exp2f((float)fi * -0.4152410118609203f); // 10000^(-2fi/64)
            #pragma unroll
            for (int mi = 0; mi < 4; mi++) {
                #pragma unroll
                for (int r = 0; r < 4; r++) {
                    const int mloc = mw + mi * 16 + quad * 4 + r;
                    const float p = (float)pos[s_base + mloc];
                    float sn, cs;
                    sincosf(p * inv_freq, &sn, &cs);
                    const float val = acc[mi][ni][r];
                    const float partner = __shfl_xor(val, 1, 64);
                    const float res = (l15 & 1) ? fmaf(partner, sn, val * cs)
                                                : fmaf(val, cs, -partner * sn);
                    smem[mloc * 136 + nw + ni * 16 + l15] = f2bf(res * qs);
                }
            }
        }
        __syncthreads();
        #pragma unroll
        for (int it = 0; it < 8; it++) {
            const int ri = it * 32 + (tid >> 3);
            const int mloc = ri & 127;
            const int hh = ri >> 7;
            const int nloc = hh * 64 + (tid & 7) * 8;
            const short8 val = *(const short8*)&smem[mloc * 136 + nloc];
            const int n = n0 + nloc;
            const int h = n >> 6, d = n & 63;
            *(short8*)(dst + ((size_t)(bb * NUM_HEADS + h) * SEQ + s_base + mloc) *
                       D_HEAD + d) = val;
        }
    }
}

// ---------------------------------------------------------------------------
// Kernel 2: causal flash attention via mfma_f32_16x16x32_bf16 (validated);
// emits bf16 A for the MFMA out-projection.
// ---------------------------------------------------------------------------
__global__ __launch_bounds__(256) void attn_mfma_kernel(
    const short* __restrict__ Qb, const short* __restrict__ Kb,
    const short* __restrict__ Vt, short* __restrict__ Ab)
{
    __shared__ __align__(16) short lK[32 * 72];
    __shared__ __align__(16) short lV[64 * 56];
    __shared__ __align__(16) short lP[4][16 * 56];

    const int tid = threadIdx.x;
    const int lane = tid & 63;
    const int wave = tid >> 6;
    const int l15 = lane & 15;
    const int quad = lane >> 4;

    const int bh = blockIdx.x & (BATCH * NUM_HEADS - 1);
    const int qt = (SEQ / 64 - 1) - (blockIdx.x >> 5);
    const int q0w = qt * 64 + wave * 16;

    const short* Kg = Kb + (size_t)bh * SEQ * D_HEAD;
    const short* Vg = Vt + (size_t)bh * D_HEAD * SEQ;

    const short* Qrow = Qb + ((size_t)bh * SEQ + q0w + l15) * D_HEAD;
    const short8 qf0 = *(const short8*)(Qrow + quad * 8);
    const short8 qf1 = *(const short8*)(Qrow + 32 + quad * 8);

    float4v o0 = {0.f, 0.f, 0.f, 0.f}, o1 = o0, o2 = o0, o3 = o0;
    float lp[4] = {0.f, 0.f, 0.f, 0.f};

    const int nt = qt * 2 + 2;
    const int krow = tid & 31, kch = tid >> 5;
    const int vrow = tid >> 2, vch = tid & 3;

    short8 kreg = *(const short8*)(Kg + (size_t)krow * D_HEAD + kch * 8);
    short8 vreg = *(const short8*)(Vg + (size_t)vrow * SEQ + vch * 8);

    for (int t = 0; t < nt; t++) {
        const int kt0 = t * 32;
        __syncthreads();
        *(short8*)&lK[krow * 72 + kch * 8] = kreg;
        *(short8*)&lV[vrow * 56 + vch * 8] = vreg;
        __syncthreads();
        if (t + 1 < nt) {
            kreg = *(const short8*)(Kg + (size_t)(kt0 + 32 + krow) * D_HEAD + kch * 8);
            vreg = *(const short8*)(Vg + (size_t)vrow * SEQ + kt0 + 32 + vch * 8);
        }
        if (kt0 > q0w + 15) continue;

        float4v s0 = {0.f, 0.f, 0.f, 0.f}, s1 = {0.f, 0.f, 0.f, 0.f};
        {
            const short8 b00 = *(const short8*)&lK[l15 * 72 + quad * 8];
            const short8 b10 = *(const short8*)&lK[(16 + l15) * 72 + quad * 8];
            s0 = __builtin_amdgcn_mfma_f32_16x16x32_bf16(qf0, b00, s0, 0, 0, 0);
            s1 = __builtin_amdgcn_mfma_f32_16x16x32_bf16(qf0, b10, s1, 0, 0, 0);
            const short8 b01 = *(const short8*)&lK[l15 * 72 + 32 + quad * 8];
            const short8 b11 = *(const short8*)&lK[(16 + l15) * 72 + 32 + quad * 8];
            s0 = __builtin_amdgcn_mfma_f32_16x16x32_bf16(qf1, b01, s0, 0, 0, 0);
            s1 = __builtin_amdgcn_mfma_f32_16x16x32_bf16(qf1, b11, s1, 0, 0, 0);
        }

        if (kt0 + 31 > q0w) {
            const int qbase = q0w + quad * 4;
            #pragma unroll
            for (int r = 0; r < 4; r++) {
                if (kt0 + l15 > qbase + r)      s0[r] = -INFINITY;
                if (kt0 + 16 + l15 > qbase + r) s1[r] = -INFINITY;
            }
        }

        float p0[4], p1[4];
        #pragma unroll
        for (int r = 0; r < 4; r++) {
            p0[r] = __expf(s0[r]);
            p1[r] = __expf(s1[r]);
            lp[r] += p0[r] + p1[r];
        }

        short* Pw = lP[wave];
        #pragma unroll
        for (int r = 0; r < 4; r++) {
            Pw[(quad * 4 + r) * 56 + l15]      = f2bf(p0[r]);
            Pw[(quad * 4 + r) * 56 + 16 + l15] = f2bf(p1[r]);
        }
        const short8 pa = *(const short8*)&lP[wave][l15 * 56 + quad * 8];

        const short8 v0 = *(const short8*)&lV[(0 * 16 + l15) * 56 + quad * 8];
        const short8 v1 = *(const short8*)&lV[(1 * 16 + l15) * 56 + quad * 8];
        const short8 v2 = *(const short8*)&lV[(2 * 16 + l15) * 56 + quad * 8];
        const short8 v3 = *(const short8*)&lV[(3 * 16 + l15) * 56 + quad * 8];
        o0 = __builtin_amdgcn_mfma_f32_16x16x32_bf16(pa, v0, o0, 0, 0, 0);
        o1 = __builtin_amdgcn_mfma_f32_16x16x32_bf16(pa, v1, o1, 0, 0, 0);
        o2 = __builtin_amdgcn_mfma_f32_16x16x32_bf16(pa, v2, o2, 0, 0, 0);
        o3 = __builtin_amdgcn_mfma_f32_16x16x32_bf16(pa, v3, o3, 0, 0, 0);
    }

    #pragma unroll
    for (int off = 1; off <= 8; off <<= 1) {
        #pragma unroll
        for (int r = 0; r < 4; r++) lp[r] += __shfl_xor(lp[r], off, 64);
    }

    const int b = bh >> 4, h = bh & 15;
    short* Ap = Ab + ((size_t)(b * SEQ) + q0w + quad * 4) * D_MODEL + h * D_HEAD;
    #pragma unroll
    for (int r = 0; r < 4; r++) {
        const float inv = 1.0f / lp[r];
        Ap[(size_t)r * D_MODEL + l15]      = f2bf(o0[r] * inv);
        Ap[(size_t)r * D_MODEL + 16 + l15] = f2bf(o1[r] * inv);
        Ap[(size_t)r * D_MODEL + 32 + l15] = f2bf(o2[r] * inv);
        Ap[(size_t)r * D_MODEL + 48 + l15] = f2bf(o3[r] * inv);
    }
}

// ---------------------------------------------------------------------------
// Kernel 3: output projection (bf16 MFMA), fp32 out. Same phase-aligned
// mapping (m fastest; single 2 MB weight shared by the whole cohort).
// ---------------------------------------------------------------------------
__global__ __launch_bounds__(256) void out_mfma_kernel(
    const short* __restrict__ Ab, const short* __restrict__ wob,
    float* __restrict__ out)
{
    __shared__ __align__(16) short smem[2 * 8192];

    const int bid = blockIdx.x;
    const int m0 = (bid & 31) * 128;
    const int n0 = (bid >> 5) * 128;

    float4v acc[4][4];
    #pragma unroll
    for (int i = 0; i < 4; i++)
        #pragma unroll
        for (int j = 0; j < 4; j++)
            acc[i][j] = (float4v){0.f, 0.f, 0.f, 0.f};

    gemm_core_db(Ab, wob, smem, m0, n0, acc);

    const int tid = threadIdx.x;
    const int lane = tid & 63;
    const int l15 = lane & 15, quad = lane >> 4;
    const int wave = tid >> 6;
    const int mw = (wave & 1) * 64, nw = (wave >> 1) * 64;

    #pragma unroll
    for (int mi = 0; mi < 4; mi++) {
        #pragma unroll
        for (int r = 0; r < 4; r++) {
            const int m = m0 + mw + mi * 16 + quad * 4 + r;
            float* op = out + (size_t)m * D_MODEL + n0 + nw + l15;
            #pragma unroll
            for (int ni = 0; ni < 4; ni++)
                op[ni * 16] = acc[mi][ni][r];
        }
    }
}

// ---------------------------------------------------------------------------
extern "C" void kernel_launch(void* const* d_in, const int* in_sizes, int n_in,
                              void* d_out, int out_size, void* d_ws, size_t ws_size,
                              hipStream_t stream)
{
    const float* x  = (const float*)d_in[0];
    const int*  pos = (const int*)d_in[1];
    const float* wq = (const float*)d_in[2];
    const float* wk = (const float*)d_in[3];
    const float* wv = (const float*)d_in[4];
    const float* wo = (const float*)d_in[5];
    float* out = (float*)d_out;

    const size_t nx = (size_t)BATCH * SEQ * D_MODEL;   // 4M
    const size_t nw = (size_t)D_MODEL * D_MODEL;       // 1M
    short* xb  = (short*)d_ws;
    short* wqb = xb + nx;
    short* wkb = wqb + nw;
    short* wvb = wkb + nw;
    short* wob = wvb + nw;
    short* Qb  = wob + nw;
    short* Kb  = Qb + nx;
    short* Vt  = Kb + nx;
    short* Ab  = Vt + nx;

    dim3 blk(256);
    cvt_bf16_kernel<<<dim3(2048, 5), blk, 0, stream>>>(x, wq, wk, wv, wo,
                                                       xb, wqb, wkb, wvb, wob);
    qkv_mfma_kernel<<<dim3(768), blk, 0, stream>>>(xb, wqb, wkb, wvb, pos,
                                                   Qb, Kb, Vt);
    attn_mfma_kernel<<<dim3(BATCH * NUM_HEADS * (SEQ / 64)), blk, 0, stream>>>(Qb, Kb, Vt, Ab);
    out_mfma_kernel<<<dim3(256), blk, 0, stream>>>(Ab, wob, out);
}

// Round 7
// 602.125 us; speedup vs baseline: 1.2626x; 1.2626x over previous
//
#include <hip/hip_runtime.h>
#include <math.h>

#define D_MODEL 1024
#define NUM_HEADS 16
#define D_HEAD 64
#define SEQ 2048
#define BATCH 2

typedef __attribute__((ext_vector_type(8))) short short8;
typedef __attribute__((ext_vector_type(4))) float float4v;

__device__ __forceinline__ short f2bf(float f) {
    unsigned u = __float_as_uint(f);
    u += 0x7FFFu + ((u >> 16) & 1u);
    return (short)(u >> 16);
}

// ---------------------------------------------------------------------------
// Kernel 0: fp32 -> bf16 conversion for x and the four weight matrices.
// ---------------------------------------------------------------------------
__global__ __launch_bounds__(256) void cvt_bf16_kernel(
    const float* __restrict__ x,  const float* __restrict__ wq,
    const float* __restrict__ wk, const float* __restrict__ wv,
    const float* __restrict__ wo,
    short* __restrict__ xb,  short* __restrict__ wqb,
    short* __restrict__ wkb, short* __restrict__ wvb,
    short* __restrict__ wob)
{
    const int a = blockIdx.y;
    const float* src = (a == 0) ? x : (a == 1) ? wq : (a == 2) ? wk : (a == 3) ? wv : wo;
    short* dst = (a == 0) ? xb : (a == 1) ? wqb : (a == 2) ? wkb : (a == 3) ? wvb : wob;
    const int n = (a == 0) ? (BATCH * SEQ * D_MODEL) : (D_MODEL * D_MODEL);
    const int i = (blockIdx.x * 256 + threadIdx.x) * 8;
    if (i >= n) return;
    const float4 v0 = *(const float4*)(src + i);
    const float4 v1 = *(const float4*)(src + i + 4);
    short8 r;
    r[0] = f2bf(v0.x); r[1] = f2bf(v0.y); r[2] = f2bf(v0.z); r[3] = f2bf(v0.w);
    r[4] = f2bf(v1.x); r[5] = f2bf(v1.y); r[6] = f2bf(v1.z); r[7] = f2bf(v1.w);
    *(short8*)(dst + i) = r;
}

// ---------------------------------------------------------------------------
// bf16 MFMA GEMM core, register-prefetch + double-buffered LDS, one barrier
// per K-step. Plain loads (no nontemporal, no DMA): this exact core in
// out_mfma_kernel measured healthy (~290 TF effective) in rounds 5/6.
// ---------------------------------------------------------------------------
__device__ __forceinline__ void gemm_core_db(
    const short* __restrict__ a, const short* __restrict__ b,
    short* smem, int m0, int n0, float4v acc[4][4])
{
    const int tid = threadIdx.x;
    const int lane = tid & 63;
    const int l15 = lane & 15, quad = lane >> 4;
    const int wave = tid >> 6;
    const int mw = (wave & 1) * 64, nw = (wave >> 1) * 64;
    const int srow = tid >> 2;            // 0..63
    const int scol = (tid & 3) * 8;       // 0,8,16,24

    const short* ag = a + (size_t)(m0 + srow) * D_MODEL + scol;
    const short* bg = b + (size_t)(n0 + srow) * D_MODEL + scol;

    short* bufA[2] = { smem,        smem + 8192 };
    short* bufB[2] = { smem + 4096, smem + 12288 };

    // prologue: stage k=0, prefetch k=1
    short8 ga0 = *(const short8*)(ag);
    short8 ga1 = *(const short8*)(ag + (size_t)64 * D_MODEL);
    short8 gb0 = *(const short8*)(bg);
    short8 gb1 = *(const short8*)(bg + (size_t)64 * D_MODEL);
    *(short8*)&bufA[0][srow * 32 + scol]        = ga0;
    *(short8*)&bufA[0][(64 + srow) * 32 + scol] = ga1;
    *(short8*)&bufB[0][srow * 32 + scol]        = gb0;
    *(short8*)&bufB[0][(64 + srow) * 32 + scol] = gb1;
    ga0 = *(const short8*)(ag + 32);
    ga1 = *(const short8*)(ag + 32 + (size_t)64 * D_MODEL);
    gb0 = *(const short8*)(bg + 32);
    gb1 = *(const short8*)(bg + 32 + (size_t)64 * D_MODEL);

    for (int k = 0; k < 32; k++) {
        __syncthreads();                       // buf[k&1] visible; buf[(k+1)&1] free
        if (k + 1 < 32) {                      // regs hold k+1 data
            short* bA = bufA[(k + 1) & 1];
            short* bB = bufB[(k + 1) & 1];
            *(short8*)&bA[srow * 32 + scol]        = ga0;
            *(short8*)&bA[(64 + srow) * 32 + scol] = ga1;
            *(short8*)&bB[srow * 32 + scol]        = gb0;
            *(short8*)&bB[(64 + srow) * 32 + scol] = gb1;
        }
        if (k + 2 < 32) {                      // prefetch k+2
            const int off = (k + 2) * 32;
            ga0 = *(const short8*)(ag + off);
            ga1 = *(const short8*)(ag + off + (size_t)64 * D_MODEL);
            gb0 = *(const short8*)(bg + off);
            gb1 = *(const short8*)(bg + off + (size_t)64 * D_MODEL);
        }
        const short* lA = bufA[k & 1];
        const short* lB = bufB[k & 1];
        short8 af[4], bf[4];
        #pragma unroll
        for (int i = 0; i < 4; i++)
            af[i] = *(const short8*)&lA[(mw + i * 16 + l15) * 32 + quad * 8];
        #pragma unroll
        for (int i = 0; i < 4; i++)
            bf[i] = *(const short8*)&lB[(nw + i * 16 + l15) * 32 + quad * 8];
        #pragma unroll
        for (int mi = 0; mi < 4; mi++)
            #pragma unroll
            for (int ni = 0; ni < 4; ni++)
                acc[mi][ni] = __builtin_amdgcn_mfma_f32_16x16x32_bf16(
                    af[mi], bf[ni], acc[mi][ni], 0, 0, 0);
    }
}

// ---------------------------------------------------------------------------
// Kernel 1: ONE projection (Q, K or V selected by the z argument) + fused
// RoPE / transpose epilogue. Launched three times back-to-back; each launch
// is configured exactly like the measured-healthy out_mfma_kernel: 256
// blocks, m-fastest mapping, single 2 MB weight (fits every per-XCD L2).
// ---------------------------------------------------------------------------
__global__ __launch_bounds__(256) void qkvz_mfma_kernel(
    const short* __restrict__ xb, const short* __restrict__ w, const int z,
    const int* __restrict__ pos,
    short* __restrict__ Qb, short* __restrict__ Kb, short* __restrict__ Vt)
{
    __shared__ __align__(16) short smem[128 * 136];   // gemm uses first 32 KB

    const int bid = blockIdx.x;
    const int m0 = (bid & 31) * 128;       // m fastest (out_mfma's mapping)
    const int n0 = (bid >> 5) * 128;

    float4v acc[4][4];
    #pragma unroll
    for (int i = 0; i < 4; i++)
        #pragma unroll
        for (int j = 0; j < 4; j++)
            acc[i][j] = (float4v){0.f, 0.f, 0.f, 0.f};

    gemm_core_db(xb, w, smem, m0, n0, acc);

    const int tid = threadIdx.x;
    const int lane = tid & 63;
    const int l15 = lane & 15, quad = lane >> 4;
    const int wave = tid >> 6;
    const int mw = (wave & 1) * 64, nw = (wave >> 1) * 64;

    const int s_base = m0 & (SEQ - 1);
    const int bb = m0 >> 11;              // tile never crosses batch (128|2048)

    __syncthreads();                      // gemm LDS reads done; reuse smem

    if (z == 2) {
        // stage transposed [n][m], stride 136
        #pragma unroll
        for (int ni = 0; ni < 4; ni++) {
            #pragma unroll
            for (int mi = 0; mi < 4; mi++) {
                #pragma unroll
                for (int r = 0; r < 4; r++)
                    smem[(nw + ni * 16 + l15) * 136 + mw + mi * 16 + quad * 4 + r] =
                        f2bf(acc[mi][ni][r]);
            }
        }
        __syncthreads();
        #pragma unroll
        for (int it = 0; it < 8; it++) {
            const int nloc = it * 16 + (tid >> 4);
            const int mloc = (tid & 15) * 8;
            const short8 val = *(const short8*)&smem[nloc * 136 + mloc];
            const int n = n0 + nloc;
            const int h = n >> 6, d = n & 63;
            *(short8*)(Vt + ((size_t)(bb * NUM_HEADS + h) * D_HEAD + d) * SEQ +
                       s_base + mloc) = val;
        }
    } else {
        short* dst = (z == 0) ? Qb : Kb;
        const float qs = (z == 0) ? 0.125f : 1.0f;
        #pragma unroll
        for (int ni = 0; ni < 4; ni++) {
            const int n = n0 + nw + ni * 16 + l15;
            const int d = n & 63;
            const int fi = d >> 1;
            const float inv_freq = exp2f((float)fi * -0.4152410118609203f); // 10000^(-2fi/64)
            #pragma unroll
            for (int mi = 0; mi < 4; mi++) {
                #pragma unroll
                for (int r = 0; r < 4; r++) {
                    const int mloc = mw + mi * 16 + quad * 4 + r;
                    const float p = (float)pos[s_base + mloc];
                    float sn, cs;
                    sincosf(p * inv_freq, &sn, &cs);
                    const float val = acc[mi][ni][r];
                    const float partner = __shfl_xor(val, 1, 64);
                    const float res = (l15 & 1) ? fmaf(partner, sn, val * cs)
                                                : fmaf(val, cs, -partner * sn);
                    smem[mloc * 136 + nw + ni * 16 + l15] = f2bf(res * qs);
                }
            }
        }
        __syncthreads();
        #pragma unroll
        for (int it = 0; it < 8; it++) {
            const int ri = it * 32 + (tid >> 3);
            const int mloc = ri & 127;
            const int hh = ri >> 7;
            const int nloc = hh * 64 + (tid & 7) * 8;
            const short8 val = *(const short8*)&smem[mloc * 136 + nloc];
            const int n = n0 + nloc;
            const int h = n >> 6, d = n & 63;
            *(short8*)(dst + ((size_t)(bb * NUM_HEADS + h) * SEQ + s_base + mloc) *
                       D_HEAD + d) = val;
        }
    }
}

// ---------------------------------------------------------------------------
// Kernel 2: causal flash attention via mfma_f32_16x16x32_bf16 (validated);
// emits bf16 A for the MFMA out-projection.
// ---------------------------------------------------------------------------
__global__ __launch_bounds__(256) void attn_mfma_kernel(
    const short* __restrict__ Qb, const short* __restrict__ Kb,
    const short* __restrict__ Vt, short* __restrict__ Ab)
{
    __shared__ __align__(16) short lK[32 * 72];
    __shared__ __align__(16) short lV[64 * 56];
    __shared__ __align__(16) short lP[4][16 * 56];

    const int tid = threadIdx.x;
    const int lane = tid & 63;
    const int wave = tid >> 6;
    const int l15 = lane & 15;
    const int quad = lane >> 4;

    const int bh = blockIdx.x & (BATCH * NUM_HEADS - 1);
    const int qt = (SEQ / 64 - 1) - (blockIdx.x >> 5);
    const int q0w = qt * 64 + wave * 16;

    const short* Kg = Kb + (size_t)bh * SEQ * D_HEAD;
    const short* Vg = Vt + (size_t)bh * D_HEAD * SEQ;

    const short* Qrow = Qb + ((size_t)bh * SEQ + q0w + l15) * D_HEAD;
    const short8 qf0 = *(const short8*)(Qrow + quad * 8);
    const short8 qf1 = *(const short8*)(Qrow + 32 + quad * 8);

    float4v o0 = {0.f, 0.f, 0.f, 0.f}, o1 = o0, o2 = o0, o3 = o0;
    float lp[4] = {0.f, 0.f, 0.f, 0.f};

    const int nt = qt * 2 + 2;
    const int krow = tid & 31, kch = tid >> 5;
    const int vrow = tid >> 2, vch = tid & 3;

    short8 kreg = *(const short8*)(Kg + (size_t)krow * D_HEAD + kch * 8);
    short8 vreg = *(const short8*)(Vg + (size_t)vrow * SEQ + vch * 8);

    for (int t = 0; t < nt; t++) {
        const int kt0 = t * 32;
        __syncthreads();
        *(short8*)&lK[krow * 72 + kch * 8] = kreg;
        *(short8*)&lV[vrow * 56 + vch * 8] = vreg;
        __syncthreads();
        if (t + 1 < nt) {
            kreg = *(const short8*)(Kg + (size_t)(kt0 + 32 + krow) * D_HEAD + kch * 8);
            vreg = *(const short8*)(Vg + (size_t)vrow * SEQ + kt0 + 32 + vch * 8);
        }
        if (kt0 > q0w + 15) continue;

        float4v s0 = {0.f, 0.f, 0.f, 0.f}, s1 = {0.f, 0.f, 0.f, 0.f};
        {
            const short8 b00 = *(const short8*)&lK[l15 * 72 + quad * 8];
            const short8 b10 = *(const short8*)&lK[(16 + l15) * 72 + quad * 8];
            s0 = __builtin_amdgcn_mfma_f32_16x16x32_bf16(qf0, b00, s0, 0, 0, 0);
            s1 = __builtin_amdgcn_mfma_f32_16x16x32_bf16(qf0, b10, s1, 0, 0, 0);
            const short8 b01 = *(const short8*)&lK[l15 * 72 + 32 + quad * 8];
            const short8 b11 = *(const short8*)&lK[(16 + l15) * 72 + 32 + quad * 8];
            s0 = __builtin_amdgcn_mfma_f32_16x16x32_bf16(qf1, b01, s0, 0, 0, 0);
            s1 = __builtin_amdgcn_mfma_f32_16x16x32_bf16(qf1, b11, s1, 0, 0, 0);
        }

        if (kt0 + 31 > q0w) {
            const int qbase = q0w + quad * 4;
            #pragma unroll
            for (int r = 0; r < 4; r++) {
                if (kt0 + l15 > qbase + r)      s0[r] = -INFINITY;
                if (kt0 + 16 + l15 > qbase + r) s1[r] = -INFINITY;
            }
        }

        float p0[4], p1[4];
        #pragma unroll
        for (int r = 0; r < 4; r++) {
            p0[r] = __expf(s0[r]);
            p1[r] = __expf(s1[r]);
            lp[r] += p0[r] + p1[r];
        }

        short* Pw = lP[wave];
        #pragma unroll
        for (int r = 0; r < 4; r++) {
            Pw[(quad * 4 + r) * 56 + l15]      = f2bf(p0[r]);
            Pw[(quad * 4 + r) * 56 + 16 + l15] = f2bf(p1[r]);
        }
        const short8 pa = *(const short8*)&lP[wave][l15 * 56 + quad * 8];

        const short8 v0 = *(const short8*)&lV[(0 * 16 + l15) * 56 + quad * 8];
        const short8 v1 = *(const short8*)&lV[(1 * 16 + l15) * 56 + quad * 8];
        const short8 v2 = *(const short8*)&lV[(2 * 16 + l15) * 56 + quad * 8];
        const short8 v3 = *(const short8*)&lV[(3 * 16 + l15) * 56 + quad * 8];
        o0 = __builtin_amdgcn_mfma_f32_16x16x32_bf16(pa, v0, o0, 0, 0, 0);
        o1 = __builtin_amdgcn_mfma_f32_16x16x32_bf16(pa, v1, o1, 0, 0, 0);
        o2 = __builtin_amdgcn_mfma_f32_16x16x32_bf16(pa, v2, o2, 0, 0, 0);
        o3 = __builtin_amdgcn_mfma_f32_16x16x32_bf16(pa, v3, o3, 0, 0, 0);
    }

    #pragma unroll
    for (int off = 1; off <= 8; off <<= 1) {
        #pragma unroll
        for (int r = 0; r < 4; r++) lp[r] += __shfl_xor(lp[r], off, 64);
    }

    const int b = bh >> 4, h = bh & 15;
    short* Ap = Ab + ((size_t)(b * SEQ) + q0w + quad * 4) * D_MODEL + h * D_HEAD;
    #pragma unroll
    for (int r = 0; r < 4; r++) {
        const float inv = 1.0f / lp[r];
        Ap[(size_t)r * D_MODEL + l15]      = f2bf(o0[r] * inv);
        Ap[(size_t)r * D_MODEL + 16 + l15] = f2bf(o1[r] * inv);
        Ap[(size_t)r * D_MODEL + 32 + l15] = f2bf(o2[r] * inv);
        Ap[(size_t)r * D_MODEL + 48 + l15] = f2bf(o3[r] * inv);
    }
}

// ---------------------------------------------------------------------------
// Kernel 3: output projection (bf16 MFMA), fp32 out. Unchanged (healthy).
// ---------------------------------------------------------------------------
__global__ __launch_bounds__(256) void out_mfma_kernel(
    const short* __restrict__ Ab, const short* __restrict__ wob,
    float* __restrict__ out)
{
    __shared__ __align__(16) short smem[2 * 8192];

    const int bid = blockIdx.x;
    const int m0 = (bid & 31) * 128;
    const int n0 = (bid >> 5) * 128;

    float4v acc[4][4];
    #pragma unroll
    for (int i = 0; i < 4; i++)
        #pragma unroll
        for (int j = 0; j < 4; j++)
            acc[i][j] = (float4v){0.f, 0.f, 0.f, 0.f};

    gemm_core_db(Ab, wob, smem, m0, n0, acc);

    const int tid = threadIdx.x;
    const int lane = tid & 63;
    const int l15 = lane & 15, quad = lane >> 4;
    const int wave = tid >> 6;
    const int mw = (wave & 1) * 64, nw = (wave >> 1) * 64;

    #pragma unroll
    for (int mi = 0; mi < 4; mi++) {
        #pragma unroll
        for (int r = 0; r < 4; r++) {
            const int m = m0 + mw + mi * 16 + quad * 4 + r;
            float* op = out + (size_t)m * D_MODEL + n0 + nw + l15;
            #pragma unroll
            for (int ni = 0; ni < 4; ni++)
                op[ni * 16] = acc[mi][ni][r];
        }
    }
}

// ---------------------------------------------------------------------------
extern "C" void kernel_launch(void* const* d_in, const int* in_sizes, int n_in,
                              void* d_out, int out_size, void* d_ws, size_t ws_size,
                              hipStream_t stream)
{
    const float* x  = (const float*)d_in[0];
    const int*  pos = (const int*)d_in[1];
    const float* wq = (const float*)d_in[2];
    const float* wk = (const float*)d_in[3];
    const float* wv = (const float*)d_in[4];
    const float* wo = (const float*)d_in[5];
    float* out = (float*)d_out;

    const size_t nx = (size_t)BATCH * SEQ * D_MODEL;   // 4M
    const size_t nw = (size_t)D_MODEL * D_MODEL;       // 1M
    short* xb  = (short*)d_ws;
    short* wqb = xb + nx;
    short* wkb = wqb + nw;
    short* wvb = wkb + nw;
    short* wob = wvb + nw;
    short* Qb  = wob + nw;
    short* Kb  = Qb + nx;
    short* Vt  = Kb + nx;
    short* Ab  = Vt + nx;

    dim3 blk(256);
    cvt_bf16_kernel<<<dim3(2048, 5), blk, 0, stream>>>(x, wq, wk, wv, wo,
                                                       xb, wqb, wkb, wvb, wob);
    qkvz_mfma_kernel<<<dim3(256), blk, 0, stream>>>(xb, wqb, 0, pos, Qb, Kb, Vt);
    qkvz_mfma_kernel<<<dim3(256), blk, 0, stream>>>(xb, wkb, 1, pos, Qb, Kb, Vt);
    qkvz_mfma_kernel<<<dim3(256), blk, 0, stream>>>(xb, wvb, 2, pos, Qb, Kb, Vt);
    attn_mfma_kernel<<<dim3(BATCH * NUM_HEADS * (SEQ / 64)), blk, 0, stream>>>(Qb, Kb, Vt, Ab);
    out_mfma_kernel<<<dim3(256), blk, 0, stream>>>(Ab, wob, out);
}

// Round 8
// 213.150 us; speedup vs baseline: 3.5668x; 2.8249x over previous
//
#include <hip/hip_runtime.h>
#include <math.h>

#define D_MODEL 1024
#define NUM_HEADS 16
#define D_HEAD 64
#define SEQ 2048
#define BATCH 2

typedef __attribute__((ext_vector_type(8))) short short8;
typedef __attribute__((ext_vector_type(4))) float float4v;

__device__ __forceinline__ short f2bf(float f) {
    unsigned u = __float_as_uint(f);
    u += 0x7FFFu + ((u >> 16) & 1u);
    return (short)(u >> 16);
}

// ---------------------------------------------------------------------------
// Kernel 0: fp32 -> bf16 conversion for x and the four weights, PLUS the
// RoPE cos/sin table (2048 pos x 32 freqs, fp32). All transcendentals live
// here (cold kernel); the hot GEMM kernels just load the table.
// ---------------------------------------------------------------------------
__global__ __launch_bounds__(256) void cvt_bf16_kernel(
    const float* __restrict__ x,  const float* __restrict__ wq,
    const float* __restrict__ wk, const float* __restrict__ wv,
    const float* __restrict__ wo, const int* __restrict__ pos,
    short* __restrict__ xb,  short* __restrict__ wqb,
    short* __restrict__ wkb, short* __restrict__ wvb,
    short* __restrict__ wob,
    float* __restrict__ costab, float* __restrict__ sintab)
{
    const int a = blockIdx.y;
    if (a == 5) {                          // RoPE table: idx = s*32 + fi
        const int idx = blockIdx.x * 256 + threadIdx.x;
        if (idx < SEQ * 32) {
            const int s = idx >> 5, fi = idx & 31;
            const float p = (float)pos[s];
            const float inv_freq = exp2f((float)fi * -0.4152410118609203f);
            float sn, cs;
            sincosf(p * inv_freq, &sn, &cs);
            costab[idx] = cs;
            sintab[idx] = sn;
        }
        return;
    }
    const float* src = (a == 0) ? x : (a == 1) ? wq : (a == 2) ? wk : (a == 3) ? wv : wo;
    short* dst = (a == 0) ? xb : (a == 1) ? wqb : (a == 2) ? wkb : (a == 3) ? wvb : wob;
    const int n = (a == 0) ? (BATCH * SEQ * D_MODEL) : (D_MODEL * D_MODEL);
    const int i = (blockIdx.x * 256 + threadIdx.x) * 8;
    if (i >= n) return;
    const float4 v0 = *(const float4*)(src + i);
    const float4 v1 = *(const float4*)(src + i + 4);
    short8 r;
    r[0] = f2bf(v0.x); r[1] = f2bf(v0.y); r[2] = f2bf(v0.z); r[3] = f2bf(v0.w);
    r[4] = f2bf(v1.x); r[5] = f2bf(v1.y); r[6] = f2bf(v1.z); r[7] = f2bf(v1.w);
    *(short8*)(dst + i) = r;
}

// ---------------------------------------------------------------------------
// bf16 MFMA GEMM core (unchanged from R7; measured healthy in out_mfma).
// ---------------------------------------------------------------------------
__device__ __forceinline__ void gemm_core_db(
    const short* __restrict__ a, const short* __restrict__ b,
    short* smem, int m0, int n0, float4v acc[4][4])
{
    const int tid = threadIdx.x;
    const int lane = tid & 63;
    const int l15 = lane & 15, quad = lane >> 4;
    const int wave = tid >> 6;
    const int mw = (wave & 1) * 64, nw = (wave >> 1) * 64;
    const int srow = tid >> 2;            // 0..63
    const int scol = (tid & 3) * 8;       // 0,8,16,24

    const short* ag = a + (size_t)(m0 + srow) * D_MODEL + scol;
    const short* bg = b + (size_t)(n0 + srow) * D_MODEL + scol;

    short* bufA[2] = { smem,        smem + 8192 };
    short* bufB[2] = { smem + 4096, smem + 12288 };

    short8 ga0 = *(const short8*)(ag);
    short8 ga1 = *(const short8*)(ag + (size_t)64 * D_MODEL);
    short8 gb0 = *(const short8*)(bg);
    short8 gb1 = *(const short8*)(bg + (size_t)64 * D_MODEL);
    *(short8*)&bufA[0][srow * 32 + scol]        = ga0;
    *(short8*)&bufA[0][(64 + srow) * 32 + scol] = ga1;
    *(short8*)&bufB[0][srow * 32 + scol]        = gb0;
    *(short8*)&bufB[0][(64 + srow) * 32 + scol] = gb1;
    ga0 = *(const short8*)(ag + 32);
    ga1 = *(const short8*)(ag + 32 + (size_t)64 * D_MODEL);
    gb0 = *(const short8*)(bg + 32);
    gb1 = *(const short8*)(bg + 32 + (size_t)64 * D_MODEL);

    for (int k = 0; k < 32; k++) {
        __syncthreads();
        if (k + 1 < 32) {
            short* bA = bufA[(k + 1) & 1];
            short* bB = bufB[(k + 1) & 1];
            *(short8*)&bA[srow * 32 + scol]        = ga0;
            *(short8*)&bA[(64 + srow) * 32 + scol] = ga1;
            *(short8*)&bB[srow * 32 + scol]        = gb0;
            *(short8*)&bB[(64 + srow) * 32 + scol] = gb1;
        }
        if (k + 2 < 32) {
            const int off = (k + 2) * 32;
            ga0 = *(const short8*)(ag + off);
            ga1 = *(const short8*)(ag + off + (size_t)64 * D_MODEL);
            gb0 = *(const short8*)(bg + off);
            gb1 = *(const short8*)(bg + off + (size_t)64 * D_MODEL);
        }
        const short* lA = bufA[k & 1];
        const short* lB = bufB[k & 1];
        short8 af[4], bf[4];
        #pragma unroll
        for (int i = 0; i < 4; i++)
            af[i] = *(const short8*)&lA[(mw + i * 16 + l15) * 32 + quad * 8];
        #pragma unroll
        for (int i = 0; i < 4; i++)
            bf[i] = *(const short8*)&lB[(nw + i * 16 + l15) * 32 + quad * 8];
        #pragma unroll
        for (int mi = 0; mi < 4; mi++)
            #pragma unroll
            for (int ni = 0; ni < 4; ni++)
                acc[mi][ni] = __builtin_amdgcn_mfma_f32_16x16x32_bf16(
                    af[mi], bf[ni], acc[mi][ni], 0, 0, 0);
    }
}

// ---------------------------------------------------------------------------
// Kernel 1a: Q or K projection. RoPE via table loads (2 loads + 1 shfl +
// 2 fma per element) — NO transcendentals, NO runtime z-branch. Structure
// mirrors the measured-healthy out_mfma_kernel.
// ---------------------------------------------------------------------------
__global__ __launch_bounds__(256) void qk_mfma_kernel(
    const short* __restrict__ xb, const short* __restrict__ w,
    const float* __restrict__ costab, const float* __restrict__ sintab,
    short* __restrict__ dst, const float qs)
{
    __shared__ __align__(16) short smem[128 * 136];   // gemm uses first 32 KB

    const int bid = blockIdx.x;
    const int m0 = (bid & 31) * 128;       // m fastest
    const int n0 = (bid >> 5) * 128;

    float4v acc[4][4];
    #pragma unroll
    for (int i = 0; i < 4; i++)
        #pragma unroll
        for (int j = 0; j < 4; j++)
            acc[i][j] = (float4v){0.f, 0.f, 0.f, 0.f};

    gemm_core_db(xb, w, smem, m0, n0, acc);

    const int tid = threadIdx.x;
    const int lane = tid & 63;
    const int l15 = lane & 15, quad = lane >> 4;
    const int wave = tid >> 6;
    const int mw = (wave & 1) * 64, nw = (wave >> 1) * 64;

    const int s_base = m0 & (SEQ - 1);
    const int bb = m0 >> 11;

    __syncthreads();                      // gemm LDS reads done; reuse smem

    #pragma unroll
    for (int ni = 0; ni < 4; ni++) {
        const int n = n0 + nw + ni * 16 + l15;
        const int d = n & 63;
        const int fi = d >> 1;
        #pragma unroll
        for (int mi = 0; mi < 4; mi++) {
            #pragma unroll
            for (int r = 0; r < 4; r++) {
                const int mloc = mw + mi * 16 + quad * 4 + r;
                const int ti = ((s_base + mloc) << 5) + fi;
                const float cs = costab[ti];
                const float sn = sintab[ti];
                const float val = acc[mi][ni][r];
                const float partner = __shfl_xor(val, 1, 64);
                const float res = (l15 & 1) ? fmaf(partner, sn, val * cs)
                                            : fmaf(val, cs, -partner * sn);
                smem[mloc * 136 + nw + ni * 16 + l15] = f2bf(res * qs);
            }
        }
    }
    __syncthreads();
    #pragma unroll
    for (int it = 0; it < 8; it++) {
        const int ri = it * 32 + (tid >> 3);
        const int mloc = ri & 127;
        const int hh = ri >> 7;
        const int nloc = hh * 64 + (tid & 7) * 8;
        const short8 val = *(const short8*)&smem[mloc * 136 + nloc];
        const int n = n0 + nloc;
        const int h = n >> 6, d = n & 63;
        *(short8*)(dst + ((size_t)(bb * NUM_HEADS + h) * SEQ + s_base + mloc) *
                   D_HEAD + d) = val;
    }
}

// ---------------------------------------------------------------------------
// Kernel 1b: V projection with transposed (B,H,D,S) store via LDS.
// ---------------------------------------------------------------------------
__global__ __launch_bounds__(256) void v_mfma_kernel(
    const short* __restrict__ xb, const short* __restrict__ w,
    short* __restrict__ Vt)
{
    __shared__ __align__(16) short smem[128 * 136];

    const int bid = blockIdx.x;
    const int m0 = (bid & 31) * 128;
    const int n0 = (bid >> 5) * 128;

    float4v acc[4][4];
    #pragma unroll
    for (int i = 0; i < 4; i++)
        #pragma unroll
        for (int j = 0; j < 4; j++)
            acc[i][j] = (float4v){0.f, 0.f, 0.f, 0.f};

    gemm_core_db(xb, w, smem, m0, n0, acc);

    const int tid = threadIdx.x;
    const int lane = tid & 63;
    const int l15 = lane & 15, quad = lane >> 4;
    const int wave = tid >> 6;
    const int mw = (wave & 1) * 64, nw = (wave >> 1) * 64;

    const int s_base = m0 & (SEQ - 1);
    const int bb = m0 >> 11;

    __syncthreads();
    #pragma unroll
    for (int ni = 0; ni < 4; ni++) {
        #pragma unroll
        for (int mi = 0; mi < 4; mi++) {
            #pragma unroll
            for (int r = 0; r < 4; r++)
                smem[(nw + ni * 16 + l15) * 136 + mw + mi * 16 + quad * 4 + r] =
                    f2bf(acc[mi][ni][r]);
        }
    }
    __syncthreads();
    #pragma unroll
    for (int it = 0; it < 8; it++) {
        const int nloc = it * 16 + (tid >> 4);
        const int mloc = (tid & 15) * 8;
        const short8 val = *(const short8*)&smem[nloc * 136 + mloc];
        const int n = n0 + nloc;
        const int h = n >> 6, d = n & 63;
        *(short8*)(Vt + ((size_t)(bb * NUM_HEADS + h) * D_HEAD + d) * SEQ +
                   s_base + mloc) = val;
    }
}

// ---------------------------------------------------------------------------
// Kernel 2: causal flash attention (validated, unchanged).
// ---------------------------------------------------------------------------
__global__ __launch_bounds__(256) void attn_mfma_kernel(
    const short* __restrict__ Qb, const short* __restrict__ Kb,
    const short* __restrict__ Vt, short* __restrict__ Ab)
{
    __shared__ __align__(16) short lK[32 * 72];
    __shared__ __align__(16) short lV[64 * 56];
    __shared__ __align__(16) short lP[4][16 * 56];

    const int tid = threadIdx.x;
    const int lane = tid & 63;
    const int wave = tid >> 6;
    const int l15 = lane & 15;
    const int quad = lane >> 4;

    const int bh = blockIdx.x & (BATCH * NUM_HEADS - 1);
    const int qt = (SEQ / 64 - 1) - (blockIdx.x >> 5);
    const int q0w = qt * 64 + wave * 16;

    const short* Kg = Kb + (size_t)bh * SEQ * D_HEAD;
    const short* Vg = Vt + (size_t)bh * D_HEAD * SEQ;

    const short* Qrow = Qb + ((size_t)bh * SEQ + q0w + l15) * D_HEAD;
    const short8 qf0 = *(const short8*)(Qrow + quad * 8);
    const short8 qf1 = *(const short8*)(Qrow + 32 + quad * 8);

    float4v o0 = {0.f, 0.f, 0.f, 0.f}, o1 = o0, o2 = o0, o3 = o0;
    float lp[4] = {0.f, 0.f, 0.f, 0.f};

    const int nt = qt * 2 + 2;
    const int krow = tid & 31, kch = tid >> 5;
    const int vrow = tid >> 2, vch = tid & 3;

    short8 kreg = *(const short8*)(Kg + (size_t)krow * D_HEAD + kch * 8);
    short8 vreg = *(const short8*)(Vg + (size_t)vrow * SEQ + vch * 8);

    for (int t = 0; t < nt; t++) {
        const int kt0 = t * 32;
        __syncthreads();
        *(short8*)&lK[krow * 72 + kch * 8] = kreg;
        *(short8*)&lV[vrow * 56 + vch * 8] = vreg;
        __syncthreads();
        if (t + 1 < nt) {
            kreg = *(const short8*)(Kg + (size_t)(kt0 + 32 + krow) * D_HEAD + kch * 8);
            vreg = *(const short8*)(Vg + (size_t)vrow * SEQ + kt0 + 32 + vch * 8);
        }
        if (kt0 > q0w + 15) continue;

        float4v s0 = {0.f, 0.f, 0.f, 0.f}, s1 = {0.f, 0.f, 0.f, 0.f};
        {
            const short8 b00 = *(const short8*)&lK[l15 * 72 + quad * 8];
            const short8 b10 = *(const short8*)&lK[(16 + l15) * 72 + quad * 8];
            s0 = __builtin_amdgcn_mfma_f32_16x16x32_bf16(qf0, b00, s0, 0, 0, 0);
            s1 = __builtin_amdgcn_mfma_f32_16x16x32_bf16(qf0, b10, s1, 0, 0, 0);
            const short8 b01 = *(const short8*)&lK[l15 * 72 + 32 + quad * 8];
            const short8 b11 = *(const short8*)&lK[(16 + l15) * 72 + 32 + quad * 8];
            s0 = __builtin_amdgcn_mfma_f32_16x16x32_bf16(qf1, b01, s0, 0, 0, 0);
            s1 = __builtin_amdgcn_mfma_f32_16x16x32_bf16(qf1, b11, s1, 0, 0, 0);
        }

        if (kt0 + 31 > q0w) {
            const int qbase = q0w + quad * 4;
            #pragma unroll
            for (int r = 0; r < 4; r++) {
                if (kt0 + l15 > qbase + r)      s0[r] = -INFINITY;
                if (kt0 + 16 + l15 > qbase + r) s1[r] = -INFINITY;
            }
        }

        float p0[4], p1[4];
        #pragma unroll
        for (int r = 0; r < 4; r++) {
            p0[r] = __expf(s0[r]);
            p1[r] = __expf(s1[r]);
            lp[r] += p0[r] + p1[r];
        }

        short* Pw = lP[wave];
        #pragma unroll
        for (int r = 0; r < 4; r++) {
            Pw[(quad * 4 + r) * 56 + l15]      = f2bf(p0[r]);
            Pw[(quad * 4 + r) * 56 + 16 + l15] = f2bf(p1[r]);
        }
        const short8 pa = *(const short8*)&lP[wave][l15 * 56 + quad * 8];

        const short8 v0 = *(const short8*)&lV[(0 * 16 + l15) * 56 + quad * 8];
        const short8 v1 = *(const short8*)&lV[(1 * 16 + l15) * 56 + quad * 8];
        const short8 v2 = *(const short8*)&lV[(2 * 16 + l15) * 56 + quad * 8];
        const short8 v3 = *(const short8*)&lV[(3 * 16 + l15) * 56 + quad * 8];
        o0 = __builtin_amdgcn_mfma_f32_16x16x32_bf16(pa, v0, o0, 0, 0, 0);
        o1 = __builtin_amdgcn_mfma_f32_16x16x32_bf16(pa, v1, o1, 0, 0, 0);
        o2 = __builtin_amdgcn_mfma_f32_16x16x32_bf16(pa, v2, o2, 0, 0, 0);
        o3 = __builtin_amdgcn_mfma_f32_16x16x32_bf16(pa, v3, o3, 0, 0, 0);
    }

    #pragma unroll
    for (int off = 1; off <= 8; off <<= 1) {
        #pragma unroll
        for (int r = 0; r < 4; r++) lp[r] += __shfl_xor(lp[r], off, 64);
    }

    const int b = bh >> 4, h = bh & 15;
    short* Ap = Ab + ((size_t)(b * SEQ) + q0w + quad * 4) * D_MODEL + h * D_HEAD;
    #pragma unroll
    for (int r = 0; r < 4; r++) {
        const float inv = 1.0f / lp[r];
        Ap[(size_t)r * D_MODEL + l15]      = f2bf(o0[r] * inv);
        Ap[(size_t)r * D_MODEL + 16 + l15] = f2bf(o1[r] * inv);
        Ap[(size_t)r * D_MODEL + 32 + l15] = f2bf(o2[r] * inv);
        Ap[(size_t)r * D_MODEL + 48 + l15] = f2bf(o3[r] * inv);
    }
}

// ---------------------------------------------------------------------------
// Kernel 3: output projection (measured healthy — unchanged).
// ---------------------------------------------------------------------------
__global__ __launch_bounds__(256) void out_mfma_kernel(
    const short* __restrict__ Ab, const short* __restrict__ wob,
    float* __restrict__ out)
{
    __shared__ __align__(16) short smem[2 * 8192];

    const int bid = blockIdx.x;
    const int m0 = (bid & 31) * 128;
    const int n0 = (bid >> 5) * 128;

    float4v acc[4][4];
    #pragma unroll
    for (int i = 0; i < 4; i++)
        #pragma unroll
        for (int j = 0; j < 4; j++)
            acc[i][j] = (float4v){0.f, 0.f, 0.f, 0.f};

    gemm_core_db(Ab, wob, smem, m0, n0, acc);

    const int tid = threadIdx.x;
    const int lane = tid & 63;
    const int l15 = lane & 15, quad = lane >> 4;
    const int wave = tid >> 6;
    const int mw = (wave & 1) * 64, nw = (wave >> 1) * 64;

    #pragma unroll
    for (int mi = 0; mi < 4; mi++) {
        #pragma unroll
        for (int r = 0; r < 4; r++) {
            const int m = m0 + mw + mi * 16 + quad * 4 + r;
            float* op = out + (size_t)m * D_MODEL + n0 + nw + l15;
            #pragma unroll
            for (int ni = 0; ni < 4; ni++)
                op[ni * 16] = acc[mi][ni][r];
        }
    }
}

// ---------------------------------------------------------------------------
extern "C" void kernel_launch(void* const* d_in, const int* in_sizes, int n_in,
                              void* d_out, int out_size, void* d_ws, size_t ws_size,
                              hipStream_t stream)
{
    const float* x  = (const float*)d_in[0];
    const int*  pos = (const int*)d_in[1];
    const float* wq = (const float*)d_in[2];
    const float* wk = (const float*)d_in[3];
    const float* wv = (const float*)d_in[4];
    const float* wo = (const float*)d_in[5];
    float* out = (float*)d_out;

    const size_t nx = (size_t)BATCH * SEQ * D_MODEL;   // 4M
    const size_t nw = (size_t)D_MODEL * D_MODEL;       // 1M
    short* xb  = (short*)d_ws;
    short* wqb = xb + nx;
    short* wkb = wqb + nw;
    short* wvb = wkb + nw;
    short* wob = wvb + nw;
    short* Qb  = wob + nw;
    short* Kb  = Qb + nx;
    short* Vt  = Kb + nx;
    short* Ab  = Vt + nx;
    float* costab = (float*)(Ab + nx);
    float* sintab = costab + SEQ * 32;

    dim3 blk(256);
    cvt_bf16_kernel<<<dim3(2048, 6), blk, 0, stream>>>(x, wq, wk, wv, wo, pos,
                                                       xb, wqb, wkb, wvb, wob,
                                                       costab, sintab);
    qk_mfma_kernel<<<dim3(256), blk, 0, stream>>>(xb, wqb, costab, sintab, Qb, 0.125f);
    qk_mfma_kernel<<<dim3(256), blk, 0, stream>>>(xb, wkb, costab, sintab, Kb, 1.0f);
    v_mfma_kernel<<<dim3(256), blk, 0, stream>>>(xb, wvb, Vt);
    attn_mfma_kernel<<<dim3(BATCH * NUM_HEADS * (SEQ / 64)), blk, 0, stream>>>(Qb, Kb, Vt, Ab);
    out_mfma_kernel<<<dim3(256), blk, 0, stream>>>(Ab, wob, out);
}

// Round 9
// 187.814 us; speedup vs baseline: 4.0479x; 1.1349x over previous
//
#include <hip/hip_runtime.h>
#include <math.h>

#define D_MODEL 1024
#define NUM_HEADS 16
#define D_HEAD 64
#define SEQ 2048
#define BATCH 2

typedef __attribute__((ext_vector_type(8))) short short8;
typedef __attribute__((ext_vector_type(4))) short short4v;
typedef __attribute__((ext_vector_type(4))) float float4v;

__device__ __forceinline__ short f2bf(float f) {
    unsigned u = __float_as_uint(f);
    u += 0x7FFFu + ((u >> 16) & 1u);
    return (short)(u >> 16);
}

// ---------------------------------------------------------------------------
// Kernel 0: fp32 -> bf16 conversion + RoPE cos/sin table (all libm here;
// NEVER in hot MFMA kernels — R7/R8 showed sincosf codegen poisons them).
// ---------------------------------------------------------------------------
__global__ __launch_bounds__(256) void cvt_bf16_kernel(
    const float* __restrict__ x,  const float* __restrict__ wq,
    const float* __restrict__ wk, const float* __restrict__ wv,
    const float* __restrict__ wo, const int* __restrict__ pos,
    short* __restrict__ xb,  short* __restrict__ wqb,
    short* __restrict__ wkb, short* __restrict__ wvb,
    short* __restrict__ wob,
    float* __restrict__ costab, float* __restrict__ sintab)
{
    const int a = blockIdx.y;
    if (a == 5) {                          // RoPE table: idx = s*32 + fi
        const int idx = blockIdx.x * 256 + threadIdx.x;
        if (idx < SEQ * 32) {
            const int s = idx >> 5, fi = idx & 31;
            const float p = (float)pos[s];
            const float inv_freq = exp2f((float)fi * -0.4152410118609203f);
            float sn, cs;
            sincosf(p * inv_freq, &sn, &cs);
            costab[idx] = cs;
            sintab[idx] = sn;
        }
        return;
    }
    const float* src = (a == 0) ? x : (a == 1) ? wq : (a == 2) ? wk : (a == 3) ? wv : wo;
    short* dst = (a == 0) ? xb : (a == 1) ? wqb : (a == 2) ? wkb : (a == 3) ? wvb : wob;
    const int n = (a == 0) ? (BATCH * SEQ * D_MODEL) : (D_MODEL * D_MODEL);
    const int i = (blockIdx.x * 256 + threadIdx.x) * 8;
    if (i >= n) return;
    const float4 v0 = *(const float4*)(src + i);
    const float4 v1 = *(const float4*)(src + i + 4);
    short8 r;
    r[0] = f2bf(v0.x); r[1] = f2bf(v0.y); r[2] = f2bf(v0.z); r[3] = f2bf(v0.w);
    r[4] = f2bf(v1.x); r[5] = f2bf(v1.y); r[6] = f2bf(v1.z); r[7] = f2bf(v1.w);
    *(short8*)(dst + i) = r;
}

// ---------------------------------------------------------------------------
// bf16 MFMA GEMM core (measured healthy; unchanged from R8).
// ---------------------------------------------------------------------------
__device__ __forceinline__ void gemm_core_db(
    const short* __restrict__ a, const short* __restrict__ b,
    short* smem, int m0, int n0, float4v acc[4][4])
{
    const int tid = threadIdx.x;
    const int lane = tid & 63;
    const int l15 = lane & 15, quad = lane >> 4;
    const int wave = tid >> 6;
    const int mw = (wave & 1) * 64, nw = (wave >> 1) * 64;
    const int srow = tid >> 2;
    const int scol = (tid & 3) * 8;

    const short* ag = a + (size_t)(m0 + srow) * D_MODEL + scol;
    const short* bg = b + (size_t)(n0 + srow) * D_MODEL + scol;

    short* bufA[2] = { smem,        smem + 8192 };
    short* bufB[2] = { smem + 4096, smem + 12288 };

    short8 ga0 = *(const short8*)(ag);
    short8 ga1 = *(const short8*)(ag + (size_t)64 * D_MODEL);
    short8 gb0 = *(const short8*)(bg);
    short8 gb1 = *(const short8*)(bg + (size_t)64 * D_MODEL);
    *(short8*)&bufA[0][srow * 32 + scol]        = ga0;
    *(short8*)&bufA[0][(64 + srow) * 32 + scol] = ga1;
    *(short8*)&bufB[0][srow * 32 + scol]        = gb0;
    *(short8*)&bufB[0][(64 + srow) * 32 + scol] = gb1;
    ga0 = *(const short8*)(ag + 32);
    ga1 = *(const short8*)(ag + 32 + (size_t)64 * D_MODEL);
    gb0 = *(const short8*)(bg + 32);
    gb1 = *(const short8*)(bg + 32 + (size_t)64 * D_MODEL);

    for (int k = 0; k < 32; k++) {
        __syncthreads();
        if (k + 1 < 32) {
            short* bA = bufA[(k + 1) & 1];
            short* bB = bufB[(k + 1) & 1];
            *(short8*)&bA[srow * 32 + scol]        = ga0;
            *(short8*)&bA[(64 + srow) * 32 + scol] = ga1;
            *(short8*)&bB[srow * 32 + scol]        = gb0;
            *(short8*)&bB[(64 + srow) * 32 + scol] = gb1;
        }
        if (k + 2 < 32) {
            const int off = (k + 2) * 32;
            ga0 = *(const short8*)(ag + off);
            ga1 = *(const short8*)(ag + off + (size_t)64 * D_MODEL);
            gb0 = *(const short8*)(bg + off);
            gb1 = *(const short8*)(bg + off + (size_t)64 * D_MODEL);
        }
        const short* lA = bufA[k & 1];
        const short* lB = bufB[k & 1];
        short8 af[4], bf[4];
        #pragma unroll
        for (int i = 0; i < 4; i++)
            af[i] = *(const short8*)&lA[(mw + i * 16 + l15) * 32 + quad * 8];
        #pragma unroll
        for (int i = 0; i < 4; i++)
            bf[i] = *(const short8*)&lB[(nw + i * 16 + l15) * 32 + quad * 8];
        #pragma unroll
        for (int mi = 0; mi < 4; mi++)
            #pragma unroll
            for (int ni = 0; ni < 4; ni++)
                acc[mi][ni] = __builtin_amdgcn_mfma_f32_16x16x32_bf16(
                    af[mi], bf[ni], acc[mi][ni], 0, 0, 0);
    }
}

// ---------------------------------------------------------------------------
// Kernel 1: fused QKV projection. z = bid>>8 (0=Q rope, 1=K rope, 2=V^T).
// 768 blocks = 3/CU -> cross-block staging/MFMA overlap. No transcendentals.
// ---------------------------------------------------------------------------
__global__ __launch_bounds__(256) void qkv_mfma_kernel(
    const short* __restrict__ xb, const short* __restrict__ wqb,
    const short* __restrict__ wkb, const short* __restrict__ wvb,
    const float* __restrict__ costab, const float* __restrict__ sintab,
    short* __restrict__ Qb, short* __restrict__ Kb, short* __restrict__ Vt)
{
    __shared__ __align__(16) short smem[128 * 136];

    const int z = blockIdx.x >> 8;
    const int bid = blockIdx.x & 255;
    const int m0 = (bid & 31) * 128;
    const int n0 = (bid >> 5) * 128;
    const short* w = (z == 0) ? wqb : (z == 1) ? wkb : wvb;

    float4v acc[4][4];
    #pragma unroll
    for (int i = 0; i < 4; i++)
        #pragma unroll
        for (int j = 0; j < 4; j++)
            acc[i][j] = (float4v){0.f, 0.f, 0.f, 0.f};

    gemm_core_db(xb, w, smem, m0, n0, acc);

    const int tid = threadIdx.x;
    const int lane = tid & 63;
    const int l15 = lane & 15, quad = lane >> 4;
    const int wave = tid >> 6;
    const int mw = (wave & 1) * 64, nw = (wave >> 1) * 64;
    const int s_base = m0 & (SEQ - 1);
    const int bb = m0 >> 11;

    __syncthreads();

    if (z == 2) {
        #pragma unroll
        for (int ni = 0; ni < 4; ni++) {
            #pragma unroll
            for (int mi = 0; mi < 4; mi++) {
                #pragma unroll
                for (int r = 0; r < 4; r++)
                    smem[(nw + ni * 16 + l15) * 136 + mw + mi * 16 + quad * 4 + r] =
                        f2bf(acc[mi][ni][r]);
            }
        }
        __syncthreads();
        #pragma unroll
        for (int it = 0; it < 8; it++) {
            const int nloc = it * 16 + (tid >> 4);
            const int mloc = (tid & 15) * 8;
            const short8 val = *(const short8*)&smem[nloc * 136 + mloc];
            const int n = n0 + nloc;
            const int h = n >> 6, d = n & 63;
            *(short8*)(Vt + ((size_t)(bb * NUM_HEADS + h) * D_HEAD + d) * SEQ +
                       s_base + mloc) = val;
        }
    } else {
        short* dst = (z == 0) ? Qb : Kb;
        const float qs = (z == 0) ? 0.125f : 1.0f;
        #pragma unroll
        for (int ni = 0; ni < 4; ni++) {
            const int n = n0 + nw + ni * 16 + l15;
            const int d = n & 63;
            const int fi = d >> 1;
            #pragma unroll
            for (int mi = 0; mi < 4; mi++) {
                #pragma unroll
                for (int r = 0; r < 4; r++) {
                    const int mloc = mw + mi * 16 + quad * 4 + r;
                    const int ti = ((s_base + mloc) << 5) + fi;
                    const float cs = costab[ti];
                    const float sn = sintab[ti];
                    const float val = acc[mi][ni][r];
                    const float partner = __shfl_xor(val, 1, 64);
                    const float res = (l15 & 1) ? fmaf(partner, sn, val * cs)
                                                : fmaf(val, cs, -partner * sn);
                    smem[mloc * 136 + nw + ni * 16 + l15] = f2bf(res * qs);
                }
            }
        }
        __syncthreads();
        #pragma unroll
        for (int it = 0; it < 8; it++) {
            const int ri = it * 32 + (tid >> 3);
            const int mloc = ri & 127;
            const int hh = ri >> 7;
            const int nloc = hh * 64 + (tid & 7) * 8;
            const short8 val = *(const short8*)&smem[mloc * 136 + nloc];
            const int n = n0 + nloc;
            const int h = n >> 6, d = n & 63;
            *(short8*)(dst + ((size_t)(bb * NUM_HEADS + h) * SEQ + s_base + mloc) *
                       D_HEAD + d) = val;
        }
    }
}

// ---------------------------------------------------------------------------
// Kernel 2: causal flash attention, restructured.
//  - S^T = K*Q^T (operands swapped): lane holds P[q=l15][k=kt0+g*16+quad*4+r]
//    -> P staging is 4x ds_write_b64 per 64 keys (was 16x ds_write_b16).
//  - 64-key tiles: 16 MFMAs per barrier pair (was 8 per pair at 32 keys).
//  - uniform 72-short LDS stride: 144 B = 4 banks mod 32 -> 2-way everywhere.
//  - lp: one accumulator/lane + 2 end-shuffles (q = l15 across quad groups).
// ---------------------------------------------------------------------------
__global__ __launch_bounds__(256) void attn_mfma_kernel(
    const short* __restrict__ Qb, const short* __restrict__ Kb,
    const short* __restrict__ Vt, short* __restrict__ Ab)
{
    __shared__ __align__(16) short lK[64 * 72];
    __shared__ __align__(16) short lV[64 * 72];
    __shared__ __align__(16) short lP[4][16 * 72];

    const int tid = threadIdx.x;
    const int lane = tid & 63;
    const int wave = tid >> 6;
    const int l15 = lane & 15;
    const int quad = lane >> 4;

    const int bh = blockIdx.x & (BATCH * NUM_HEADS - 1);
    const int qt = (SEQ / 64 - 1) - (blockIdx.x >> 5);   // longest first
    const int q0w = qt * 64 + wave * 16;
    const int qcmp = q0w + l15;

    const short* Kg = Kb + (size_t)bh * SEQ * D_HEAD;
    const short* Vg = Vt + (size_t)bh * D_HEAD * SEQ;

    const short* Qrow = Qb + ((size_t)bh * SEQ + q0w + l15) * D_HEAD;
    const short8 qf0 = *(const short8*)(Qrow + quad * 8);
    const short8 qf1 = *(const short8*)(Qrow + 32 + quad * 8);

    float4v o0 = {0.f, 0.f, 0.f, 0.f}, o1 = o0, o2 = o0, o3 = o0;
    float lp = 0.f;

    const int nt = qt + 1;                 // 64-key tiles
    const int srow = tid >> 2;             // 0..63
    const int sch = (tid & 3) * 8;         // 0,8,16,24 shorts

    short8 k0 = *(const short8*)(Kg + (size_t)srow * D_HEAD + sch);
    short8 k1 = *(const short8*)(Kg + (size_t)srow * D_HEAD + sch + 32);
    short8 v0 = *(const short8*)(Vg + (size_t)srow * SEQ + sch);
    short8 v1 = *(const short8*)(Vg + (size_t)srow * SEQ + sch + 32);

    for (int t = 0; t < nt; t++) {
        const int kt0 = t * 64;
        __syncthreads();
        *(short8*)&lK[srow * 72 + sch]      = k0;
        *(short8*)&lK[srow * 72 + sch + 32] = k1;
        *(short8*)&lV[srow * 72 + sch]      = v0;
        *(short8*)&lV[srow * 72 + sch + 32] = v1;
        __syncthreads();
        if (t + 1 < nt) {
            k0 = *(const short8*)(Kg + (size_t)(kt0 + 64 + srow) * D_HEAD + sch);
            k1 = *(const short8*)(Kg + (size_t)(kt0 + 64 + srow) * D_HEAD + sch + 32);
            v0 = *(const short8*)(Vg + (size_t)srow * SEQ + kt0 + 64 + sch);
            v1 = *(const short8*)(Vg + (size_t)srow * SEQ + kt0 + 64 + sch + 32);
        }

        // S^T = K Q^T per 16-key group g
        short* Pw = lP[wave];
        #pragma unroll
        for (int g = 0; g < 4; g++) {
            float4v s = {0.f, 0.f, 0.f, 0.f};
            const short8 ka = *(const short8*)&lK[(g * 16 + l15) * 72 + quad * 8];
            s = __builtin_amdgcn_mfma_f32_16x16x32_bf16(ka, qf0, s, 0, 0, 0);
            const short8 kb = *(const short8*)&lK[(g * 16 + l15) * 72 + 32 + quad * 8];
            s = __builtin_amdgcn_mfma_f32_16x16x32_bf16(kb, qf1, s, 0, 0, 0);

            const int kbase = kt0 + g * 16 + quad * 4;
            short4v pk;
            #pragma unroll
            for (int r = 0; r < 4; r++) {
                const float e = (kbase + r <= qcmp) ? __expf(s[r]) : 0.f;
                lp += e;
                pk[r] = f2bf(e);
            }
            *(short4v*)&Pw[l15 * 72 + g * 16 + quad * 4] = pk;
        }

        const short8 pa0 = *(const short8*)&lP[wave][l15 * 72 + quad * 8];
        const short8 pa1 = *(const short8*)&lP[wave][l15 * 72 + 32 + quad * 8];

        {
            const short8 va = *(const short8*)&lV[(0 * 16 + l15) * 72 + quad * 8];
            const short8 vb = *(const short8*)&lV[(0 * 16 + l15) * 72 + 32 + quad * 8];
            o0 = __builtin_amdgcn_mfma_f32_16x16x32_bf16(pa0, va, o0, 0, 0, 0);
            o0 = __builtin_amdgcn_mfma_f32_16x16x32_bf16(pa1, vb, o0, 0, 0, 0);
        }
        {
            const short8 va = *(const short8*)&lV[(1 * 16 + l15) * 72 + quad * 8];
            const short8 vb = *(const short8*)&lV[(1 * 16 + l15) * 72 + 32 + quad * 8];
            o1 = __builtin_amdgcn_mfma_f32_16x16x32_bf16(pa0, va, o1, 0, 0, 0);
            o1 = __builtin_amdgcn_mfma_f32_16x16x32_bf16(pa1, vb, o1, 0, 0, 0);
        }
        {
            const short8 va = *(const short8*)&lV[(2 * 16 + l15) * 72 + quad * 8];
            const short8 vb = *(const short8*)&lV[(2 * 16 + l15) * 72 + 32 + quad * 8];
            o2 = __builtin_amdgcn_mfma_f32_16x16x32_bf16(pa0, va, o2, 0, 0, 0);
            o2 = __builtin_amdgcn_mfma_f32_16x16x32_bf16(pa1, vb, o2, 0, 0, 0);
        }
        {
            const short8 va = *(const short8*)&lV[(3 * 16 + l15) * 72 + quad * 8];
            const short8 vb = *(const short8*)&lV[(3 * 16 + l15) * 72 + 32 + quad * 8];
            o3 = __builtin_amdgcn_mfma_f32_16x16x32_bf16(pa0, va, o3, 0, 0, 0);
            o3 = __builtin_amdgcn_mfma_f32_16x16x32_bf16(pa1, vb, o3, 0, 0, 0);
        }
    }

    // lp totals: q = l15 replicated across quad groups
    lp += __shfl_xor(lp, 16, 64);
    lp += __shfl_xor(lp, 32, 64);

    const int b = bh >> 4, h = bh & 15;
    short* Ap = Ab + ((size_t)(b * SEQ) + q0w + quad * 4) * D_MODEL + h * D_HEAD;
    #pragma unroll
    for (int r = 0; r < 4; r++) {
        const float inv = 1.0f / __shfl(lp, quad * 4 + r, 64);
        Ap[(size_t)r * D_MODEL + l15]      = f2bf(o0[r] * inv);
        Ap[(size_t)r * D_MODEL + 16 + l15] = f2bf(o1[r] * inv);
        Ap[(size_t)r * D_MODEL + 32 + l15] = f2bf(o2[r] * inv);
        Ap[(size_t)r * D_MODEL + 48 + l15] = f2bf(o3[r] * inv);
    }
}

// ---------------------------------------------------------------------------
// Kernel 3: output projection (measured healthy — unchanged; control group).
// ---------------------------------------------------------------------------
__global__ __launch_bounds__(256) void out_mfma_kernel(
    const short* __restrict__ Ab, const short* __restrict__ wob,
    float* __restrict__ out)
{
    __shared__ __align__(16) short smem[2 * 8192];

    const int bid = blockIdx.x;
    const int m0 = (bid & 31) * 128;
    const int n0 = (bid >> 5) * 128;

    float4v acc[4][4];
    #pragma unroll
    for (int i = 0; i < 4; i++)
        #pragma unroll
        for (int j = 0; j < 4; j++)
            acc[i][j] = (float4v){0.f, 0.f, 0.f, 0.f};

    gemm_core_db(Ab, wob, smem, m0, n0, acc);

    const int tid = threadIdx.x;
    const int lane = tid & 63;
    const int l15 = lane & 15, quad = lane >> 4;
    const int wave = tid >> 6;
    const int mw = (wave & 1) * 64, nw = (wave >> 1) * 64;

    #pragma unroll
    for (int mi = 0; mi < 4; mi++) {
        #pragma unroll
        for (int r = 0; r < 4; r++) {
            const int m = m0 + mw + mi * 16 + quad * 4 + r;
            float* op = out + (size_t)m * D_MODEL + n0 + nw + l15;
            #pragma unroll
            for (int ni = 0; ni < 4; ni++)
                op[ni * 16] = acc[mi][ni][r];
        }
    }
}

// ---------------------------------------------------------------------------
extern "C" void kernel_launch(void* const* d_in, const int* in_sizes, int n_in,
                              void* d_out, int out_size, void* d_ws, size_t ws_size,
                              hipStream_t stream)
{
    const float* x  = (const float*)d_in[0];
    const int*  pos = (const int*)d_in[1];
    const float* wq = (const float*)d_in[2];
    const float* wk = (const float*)d_in[3];
    const float* wv = (const float*)d_in[4];
    const float* wo = (const float*)d_in[5];
    float* out = (float*)d_out;

    const size_t nx = (size_t)BATCH * SEQ * D_MODEL;   // 4M
    const size_t nw = (size_t)D_MODEL * D_MODEL;       // 1M
    short* xb  = (short*)d_ws;
    short* wqb = xb + nx;
    short* wkb = wqb + nw;
    short* wvb = wkb + nw;
    short* wob = wvb + nw;
    short* Qb  = wob + nw;
    short* Kb  = Qb + nx;
    short* Vt  = Kb + nx;
    short* Ab  = Vt + nx;
    float* costab = (float*)(Ab + nx);
    float* sintab = costab + SEQ * 32;

    dim3 blk(256);
    cvt_bf16_kernel<<<dim3(2048, 6), blk, 0, stream>>>(x, wq, wk, wv, wo, pos,
                                                       xb, wqb, wkb, wvb, wob,
                                                       costab, sintab);
    qkv_mfma_kernel<<<dim3(768), blk, 0, stream>>>(xb, wqb, wkb, wvb,
                                                   costab, sintab, Qb, Kb, Vt);
    attn_mfma_kernel<<<dim3(BATCH * NUM_HEADS * (SEQ / 64)), blk, 0, stream>>>(Qb, Kb, Vt, Ab);
    out_mfma_kernel<<<dim3(256), blk, 0, stream>>>(Ab, wob, out);
}